// Round 7
// baseline (1074.585 us; speedup 1.0000x reference)
//
#include <hip/hip_runtime.h>
#include <hip/hip_bf16.h>

typedef unsigned int u32;
typedef unsigned short u16;
typedef unsigned char u8;
typedef __attribute__((ext_vector_type(8))) __bf16 bfrag;   // 8 bf16 = 4 VGPRs (MFMA A/B operand)
typedef __attribute__((ext_vector_type(4))) float f32x4;    // MFMA C/D
typedef __attribute__((ext_vector_type(2))) float f32x2;

#define T_STEPS 4
#define N_NODES 50000
#define E_EDGES 1600000
#define HID 128
#define OUT_CH 16

#define NB 128                   // hist blocks; chunk = E/NB
#define CHUNK (E_EDGES / NB)     // 12500
#define NPAIR (N_NODES / 2)      // 25000 packed u16-pair histogram entries
#define SCAN4 13                 // int4s per thread in scan (1024*13=13312 >= 12500)

// ---- workspace layout (bytes) ----
#define OFF_H     0u            // h fp8 [N*128] u8           = 6,400,000 (fp8: 2x less gather traffic vs bf16)
#define OFF_DEG   12800000u     // deg [13312 int4 padded]    = 212,992
#define OFF_RS    13012992u     // row_start [13312 int4]     = 212,992
#define OFF_ZPAD  13225984u     // z_sum padded [128*32] f32  = 16,384
#define OFF_CSR   13242368u     // csr src [E] u16            = 3,200,000
#define OFF_HST   16442368u     // h_state [128] f32          = 512
#define OFF_WB    16442880u     // W_gcn bf16 [128*128]       = 32,768
#define OFF_RANKS 16475648u     // ranks [E] u16              = 3,200,000
#define OFF_HIST  19675648u     // hist [NB][NPAIR] u32       = 12,800,000 (end ~32.5 MB)

__device__ __forceinline__ u8 f32_to_fp8(float v) {
    return (u8)(__builtin_amdgcn_cvt_pk_fp8_f32(v, v, 0, 0) & 0xFF);
}

// one-shot: W fp32 -> bf16 (32 KB, L1-resident for the GEMM)
__global__ void wbf_kernel(const float* __restrict__ W, __bf16* __restrict__ wb) {
    const int i = blockIdx.x * 256 + threadIdx.x;   // 16384
    wb[i] = (__bf16)W[i];
}

// h = fp8(x @ W^T + b) via MFMA 16x16x32 bf16.
// Block = 16-row m-tile (3125 blocks), 4 waves; wave wv covers output cols [32wv,32wv+32).
// Frag layouts (m89/m120-verified): A[m=lane&15][k=(lane>>4)*8+j],
// B[n=lane&15][k=(lane>>4)*8+j], C/D row=(lane>>4)*4+reg, col=lane&15.
__global__ __launch_bounds__(256) void gemm_mfma_kernel(const float* __restrict__ x,
                                                        const __bf16* __restrict__ wb,
                                                        const float* __restrict__ b,
                                                        u8* __restrict__ h8) {
    const int lane = threadIdx.x & 63;
    const int wv   = threadIdx.x >> 6;      // 0..3 -> n-slice
    const int r16  = lane & 15;
    const int quad = lane >> 4;
    const int mb   = blockIdx.x;            // rows [16mb, 16mb+16)

    bfrag Bf[2][4];
#pragma unroll
    for (int nt = 0; nt < 2; ++nt) {
        const int c = wv * 32 + nt * 16 + r16;
#pragma unroll
        for (int ks = 0; ks < 4; ++ks)
            Bf[nt][ks] = *(const bfrag*)(wb + c * 128 + ks * 32 + quad * 8);
    }

    const float* xp = x + (size_t)(mb * 16 + r16) * 128 + quad * 8;
    bfrag Af[4];
#pragma unroll
    for (int ks = 0; ks < 4; ++ks) {
        const float* ap = xp + ks * 32;
#pragma unroll
        for (int j = 0; j < 8; ++j) Af[ks][j] = (__bf16)ap[j];
    }

    f32x4 acc0 = {0.f, 0.f, 0.f, 0.f};
    f32x4 acc1 = {0.f, 0.f, 0.f, 0.f};
#pragma unroll
    for (int ks = 0; ks < 4; ++ks) {
        acc0 = __builtin_amdgcn_mfma_f32_16x16x32_bf16(Af[ks], Bf[0][ks], acc0, 0, 0, 0);
        acc1 = __builtin_amdgcn_mfma_f32_16x16x32_bf16(Af[ks], Bf[1][ks], acc1, 0, 0, 0);
    }

    const int c0 = wv * 32 + r16;
    const float b0 = b[c0], b1 = b[c0 + 16];
#pragma unroll
    for (int r = 0; r < 4; ++r) {
        const size_t row = (size_t)(mb * 16 + quad * 4 + r) * 128;
        h8[row + c0]      = f32_to_fp8(acc0[r] + b0);
        h8[row + c0 + 16] = f32_to_fp8(acc1[r] + b1);
    }
}

// Block b: LDS histogram of its 12500-edge chunk (u16 counts packed 2/u32),
// LDS-atomic return = local rank. No global atomics (R3 lesson: 1.6M
// device-scope atomics = 103 MB EA round-trips).
__global__ __launch_bounds__(512) void hist_rank_kernel(const int* __restrict__ dst,
                                                        u32* __restrict__ hist,
                                                        u16* __restrict__ ranks) {
    __shared__ u32 hloc[NPAIR / 2];          // 12500 u32 = 50 KB
    const int b = blockIdx.x;
    const int base = b * CHUNK;
    u32* row = hist + (size_t)b * NPAIR;

#pragma unroll
    for (int half = 0; half < 2; ++half) {
        for (int j = threadIdx.x; j < NPAIR / 2; j += 512) hloc[j] = 0;
        __syncthreads();
        const int jlo = half * (NPAIR / 2);
        for (int i = threadIdx.x; i < CHUNK; i += 512) {
            const int d = dst[base + i];
            const int j = d >> 1;
            if ((j >= jlo) && (j < jlo + NPAIR / 2)) {
                const u32 inc = (d & 1) ? 0x10000u : 1u;
                const u32 old = atomicAdd(&hloc[j - jlo], inc);
                ranks[base + i] = (u16)((old >> ((d & 1) * 16)) & 0xFFFFu);
            }
        }
        __syncthreads();
        for (int j = threadIdx.x; j < NPAIR / 2; j += 512) row[jlo + j] = hloc[j];
        __syncthreads();
    }
}

// In-place exclusive scan over the NB block-rows for each node pair; emits deg.
__global__ void colscan_kernel(u32* __restrict__ hist, int* __restrict__ deg) {
    const int j = blockIdx.x * blockDim.x + threadIdx.x;
    if (j >= NPAIR) return;
    u32 lo = 0, hi = 0;
    u32* p = hist + j;
#pragma unroll 8
    for (int b = 0; b < NB; ++b) {
        const u32 v = p[(size_t)b * NPAIR];
        p[(size_t)b * NPAIR] = lo | (hi << 16);
        lo += v & 0xFFFFu;
        hi += v >> 16;
    }
    deg[2 * j]     = (int)lo;
    deg[2 * j + 1] = (int)hi;
}

// Single-block scan, fully unrolled + vectorized (R5 lesson: dynamic-trip
// scalar loops serialize ~100 round-trips). 13 int4/thread, all loads in
// flight before one waitcnt; deg tail pre-zeroed so row_start[50000]=E.
__global__ __launch_bounds__(1024) void scan_kernel(const int4* __restrict__ deg4,
                                                    int4* __restrict__ rs4) {
    __shared__ int part[1024];
    const int tid = threadIdx.x;
    int4 v[SCAN4];
#pragma unroll
    for (int j = 0; j < SCAN4; ++j) v[j] = deg4[tid * SCAN4 + j];
    int s = 0;
#pragma unroll
    for (int j = 0; j < SCAN4; ++j) s += v[j].x + v[j].y + v[j].z + v[j].w;
    part[tid] = s;
    __syncthreads();
    for (int d = 1; d < 1024; d <<= 1) {
        const int t = (tid >= d) ? part[tid - d] : 0;
        __syncthreads();
        part[tid] += t;
        __syncthreads();
    }
    int run = (tid == 0) ? 0 : part[tid - 1];
#pragma unroll
    for (int j = 0; j < SCAN4; ++j) {
        int4 o;
        o.x = run; run += v[j].x;
        o.y = run; run += v[j].y;
        o.z = run; run += v[j].z;
        o.w = run; run += v[j].w;
        rs4[tid * SCAN4 + j] = o;
    }
}

// pos = row_start[d] + colscan[b][d] + local_rank  -- atomic-free CSR fill.
__global__ __launch_bounds__(256) void fill_kernel(const int* __restrict__ src,
                                                   const int* __restrict__ dst,
                                                   const u16* __restrict__ ranks,
                                                   const int* __restrict__ row_start,
                                                   const u32* __restrict__ hist,
                                                   u16* __restrict__ csr) {
    const int b = blockIdx.x >> 2;
    const int q = blockIdx.x & 3;
    const u32* cs = hist + (size_t)b * NPAIR;
    const int base = b * CHUNK + q * (CHUNK / 4);
    for (int i = threadIdx.x; i < CHUNK / 4; i += 256) {
        const int d = dst[base + i];
        const int s = src[base + i];
        const int r = ranks[base + i];
        const int off = (int)((cs[d >> 1] >> ((d & 1) * 16)) & 0xFFFFu);
        csr[row_start[d] + off + r] = (u16)s;
    }
}

// One wave per dst node, 2 edges per wave-load: half-wave 0 reads row s0,
// half-wave 1 reads s1 (both wave-uniform). Lane q=lane&31 holds 4 fp8
// channels (one dword) -> 128B/row, h8=6.4MB mostly L2-resident (R6 lesson:
// 256B bf16 rows missed the 4MB/XCD L2 -> 147 MB miss traffic).
__global__ __launch_bounds__(256) void gather_kernel(const u32* __restrict__ h8d,
                                                     const int* __restrict__ row_start,
                                                     const u16* __restrict__ csr,
                                                     float* __restrict__ z_pad) {
    const int lane = threadIdx.x & 63;
    const int wv   = __builtin_amdgcn_readfirstlane((int)(threadIdx.x >> 6));
    const int q    = lane & 31;
    const bool h0  = lane < 32;
    const int gw   = blockIdx.x * 4 + wv;
    const int nw   = gridDim.x * 4;

    float z0 = 0.f, z1 = 0.f, z2 = 0.f, z3 = 0.f;
    for (int n = gw; n < N_NODES; n += nw) {
        const int rs  = row_start[n];
        const int cnt = row_start[n + 1] - rs;
        // self loop: count once (half 0 only)
        const u32 us = h8d[n * 32 + q];
        const f32x2 slo = __builtin_amdgcn_cvt_pk_f32_fp8(us, 0);
        const f32x2 shi = __builtin_amdgcn_cvt_pk_f32_fp8(us, 1);
        float a0 = h0 ? slo.x : 0.f;
        float a1 = h0 ? slo.y : 0.f;
        float a2 = h0 ? shi.x : 0.f;
        float a3 = h0 ? shi.y : 0.f;

        const u16* lst = csr + rs;
        int i = 0;
        for (; i + 2 <= cnt; i += 2) {
            const int s0 = lst[i], s1 = lst[i + 1];
            const int s = h0 ? s0 : s1;
            const u32 u = h8d[s * 32 + q];
            const f32x2 lo = __builtin_amdgcn_cvt_pk_f32_fp8(u, 0);
            const f32x2 hi = __builtin_amdgcn_cvt_pk_f32_fp8(u, 1);
            a0 += lo.x; a1 += lo.y; a2 += hi.x; a3 += hi.y;
        }
        if (i < cnt) {
            const int s = lst[i];
            const u32 u = h8d[s * 32 + q];
            const f32x2 lo = __builtin_amdgcn_cvt_pk_f32_fp8(u, 0);
            const f32x2 hi = __builtin_amdgcn_cvt_pk_f32_fp8(u, 1);
            if (h0) { a0 += lo.x; a1 += lo.y; a2 += hi.x; a3 += hi.y; }
        }
        // combine halves (lane q <-> lane q+32)
        a0 += __shfl_xor(a0, 32);
        a1 += __shfl_xor(a1, 32);
        a2 += __shfl_xor(a2, 32);
        a3 += __shfl_xor(a3, 32);
        const float inv = 1.0f / (float)(cnt + 1);
        z0 += fmaxf(a0 * inv, 0.f);
        z1 += fmaxf(a1 * inv, 0.f);
        z2 += fmaxf(a2 * inv, 0.f);
        z3 += fmaxf(a3 * inv, 0.f);
    }

    // both halves hold identical z -> sum over all 64 lanes counts 2x; scale 0.5
    __shared__ float red[4][64][4];
    red[wv][lane][0] = z0;
    red[wv][lane][1] = z1;
    red[wv][lane][2] = z2;
    red[wv][lane][3] = z3;
    __syncthreads();
    if (threadIdx.x < 128) {
        const int c = threadIdx.x;          // channel
        const int g = c >> 2, m = c & 3;
        float s = 0.f;
#pragma unroll
        for (int w = 0; w < 4; ++w) s += red[w][g][m] + red[w][g + 32][m];
        atomicAdd(&z_pad[c * 32], 0.5f * s);   // 128 slots, 128B apart
    }
}

__global__ __launch_bounds__(512) void gru_kernel(const float* __restrict__ z_pad,
                                                  const float* __restrict__ W_ih,
                                                  const float* __restrict__ W_hh,
                                                  const float* __restrict__ b_ih,
                                                  const float* __restrict__ b_hh,
                                                  float* __restrict__ h_state,
                                                  const float* __restrict__ W_cls,
                                                  const float* __restrict__ b_cls,
                                                  float* __restrict__ out,
                                                  int do_cls) {
    __shared__ float zm[128], hs[128], gi[384], gh[384], hn[128];
    const int tid = threadIdx.x;
    if (tid < 128) {
        zm[tid] = z_pad[tid * 32] * (1.0f / (float)N_NODES);
        hs[tid] = h_state[tid];
    }
    __syncthreads();
    if (tid < 384) {
        float a = b_ih[tid], g = b_hh[tid];
        const float* wi = W_ih + tid * 128;
        const float* wh = W_hh + tid * 128;
#pragma unroll 8
        for (int k = 0; k < 128; ++k) {
            a = fmaf(zm[k], wi[k], a);
            g = fmaf(hs[k], wh[k], g);
        }
        gi[tid] = a;
        gh[tid] = g;
    }
    __syncthreads();
    if (tid < 128) {
        const float r  = 1.f / (1.f + expf(-(gi[tid] + gh[tid])));
        const float zg = 1.f / (1.f + expf(-(gi[128 + tid] + gh[128 + tid])));
        const float ng = tanhf(gi[256 + tid] + r * gh[256 + tid]);
        const float hv = (1.f - zg) * ng + zg * hs[tid];
        h_state[tid] = hv;
        hn[tid] = hv;
    }
    __syncthreads();
    if (do_cls && tid < OUT_CH) {
        float a = b_cls[tid];
        const float* wc = W_cls + tid * 128;
#pragma unroll 8
        for (int k = 0; k < 128; ++k) a = fmaf(hn[k], wc[k], a);
        out[tid] = a;
    }
}

extern "C" void kernel_launch(void* const* d_in, const int* in_sizes, int n_in,
                              void* d_out, int out_size, void* d_ws, size_t ws_size,
                              hipStream_t stream) {
    const float* xs    = (const float*)d_in[0];
    const int*   edges = (const int*)d_in[1];
    const float* W_gcn = (const float*)d_in[2];
    const float* b_gcn = (const float*)d_in[3];
    const float* W_ih  = (const float*)d_in[4];
    const float* W_hh  = (const float*)d_in[5];
    const float* b_ih  = (const float*)d_in[6];
    const float* b_hh  = (const float*)d_in[7];
    const float* W_cls = (const float*)d_in[8];
    const float* b_cls = (const float*)d_in[9];
    float* out = (float*)d_out;

    char* ws = (char*)d_ws;
    u8*    h8        = (u8*)(ws + OFF_H);
    int*   deg       = (int*)(ws + OFF_DEG);
    int*   row_start = (int*)(ws + OFF_RS);
    float* z_pad     = (float*)(ws + OFF_ZPAD);
    u16*   csr       = (u16*)(ws + OFF_CSR);
    float* h_state   = (float*)(ws + OFF_HST);
    __bf16* wb       = (__bf16*)(ws + OFF_WB);
    u16*   ranks     = (u16*)(ws + OFF_RANKS);
    u32*   hist      = (u32*)(ws + OFF_HIST);

    hipMemsetAsync(h_state, 0, 128 * sizeof(float), stream);
    // zero deg tail [50000, 13312*4): ws re-poisoned 0xAA before every launch
    hipMemsetAsync((char*)deg + 200000, 0, 13312 * 16 - 200000, stream);
    wbf_kernel<<<64, 256, 0, stream>>>(W_gcn, wb);

    for (int t = 0; t < T_STEPS; ++t) {
        const float* x_t  = xs + (size_t)t * N_NODES * 128;
        const int* src_t  = edges + (size_t)t * 2 * E_EDGES;
        const int* dst_t  = src_t + E_EDGES;

        hipMemsetAsync(z_pad, 0, 16384, stream);

        gemm_mfma_kernel<<<3125, 256, 0, stream>>>(x_t, wb, b_gcn, h8);
        hist_rank_kernel<<<NB, 512, 0, stream>>>(dst_t, hist, ranks);
        colscan_kernel<<<(NPAIR + 255) / 256, 256, 0, stream>>>(hist, deg);
        scan_kernel<<<1, 1024, 0, stream>>>((const int4*)deg, (int4*)row_start);
        fill_kernel<<<NB * 4, 256, 0, stream>>>(src_t, dst_t, ranks, row_start, hist, csr);
        gather_kernel<<<2048, 256, 0, stream>>>((const u32*)h8, row_start, csr, z_pad);
        gru_kernel<<<1, 512, 0, stream>>>(z_pad, W_ih, W_hh, b_ih, b_hh, h_state,
                                          W_cls, b_cls, out, (t == T_STEPS - 1) ? 1 : 0);
    }
}

// Round 8
// 940.092 us; speedup vs baseline: 1.1431x; 1.1431x over previous
//
#include <hip/hip_runtime.h>
#include <hip/hip_bf16.h>

typedef unsigned int u32;
typedef unsigned short u16;
typedef unsigned char u8;
typedef __attribute__((ext_vector_type(8))) __bf16 bfrag;   // 8 bf16 = 4 VGPRs (MFMA A/B operand)
typedef __attribute__((ext_vector_type(4))) float f32x4;    // MFMA C/D
typedef __attribute__((ext_vector_type(2))) float f32x2;

#define T_STEPS 4
#define N_NODES 50000
#define E_EDGES 1600000
#define HID 128
#define OUT_CH 16

#define NB 128                   // hist blocks; chunk = E/NB
#define CHUNK (E_EDGES / NB)     // 12500
#define NPAIR (N_NODES / 2)      // 25000 packed u16-pair histogram entries
#define SCAN4 13                 // int4s per thread in scan (1024*13=13312 >= 12500)

// ---- workspace layout (bytes) ----
#define OFF_H     0u            // h fp8 [N*128] u8           = 6,400,000
#define OFF_DEG   12800000u     // deg [13312 int4 padded]    = 212,992
#define OFF_RS    13012992u     // row_start [13312 int4]     = 212,992
#define OFF_ZPAD  13225984u     // z_sum padded [128*32] f32  = 16,384
#define OFF_CSR   13242368u     // csr src [E] u16            = 3,200,000
#define OFF_HST   16442368u     // h_state [128] f32          = 512
#define OFF_WB    16442880u     // W_gcn bf16 [128*128]       = 32,768
#define OFF_RANKS 16475648u     // ranks [E] u16              = 3,200,000
#define OFF_HIST  19675648u     // hist [NB][NPAIR] u32       = 12,800,000 (end ~32.5 MB)

__device__ __forceinline__ u8 f32_to_fp8(float v) {
    return (u8)(__builtin_amdgcn_cvt_pk_fp8_f32(v, v, 0, 0) & 0xFF);
}

// one-shot: W fp32 -> bf16 (32 KB, L1-resident for the GEMM)
__global__ void wbf_kernel(const float* __restrict__ W, __bf16* __restrict__ wb) {
    const int i = blockIdx.x * 256 + threadIdx.x;   // 16384
    wb[i] = (__bf16)W[i];
}

// h = fp8(x @ W^T + b) via MFMA 16x16x32 bf16.
// Frag layouts (m89/m120-verified): A[m=lane&15][k=(lane>>4)*8+j],
// B[n=lane&15][k=(lane>>4)*8+j], C/D row=(lane>>4)*4+reg, col=lane&15.
__global__ __launch_bounds__(256) void gemm_mfma_kernel(const float* __restrict__ x,
                                                        const __bf16* __restrict__ wb,
                                                        const float* __restrict__ b,
                                                        u8* __restrict__ h8) {
    const int lane = threadIdx.x & 63;
    const int wv   = threadIdx.x >> 6;      // 0..3 -> n-slice
    const int r16  = lane & 15;
    const int quad = lane >> 4;
    const int mb   = blockIdx.x;            // rows [16mb, 16mb+16)

    bfrag Bf[2][4];
#pragma unroll
    for (int nt = 0; nt < 2; ++nt) {
        const int c = wv * 32 + nt * 16 + r16;
#pragma unroll
        for (int ks = 0; ks < 4; ++ks)
            Bf[nt][ks] = *(const bfrag*)(wb + c * 128 + ks * 32 + quad * 8);
    }

    const float* xp = x + (size_t)(mb * 16 + r16) * 128 + quad * 8;
    bfrag Af[4];
#pragma unroll
    for (int ks = 0; ks < 4; ++ks) {
        const float* ap = xp + ks * 32;
#pragma unroll
        for (int j = 0; j < 8; ++j) Af[ks][j] = (__bf16)ap[j];
    }

    f32x4 acc0 = {0.f, 0.f, 0.f, 0.f};
    f32x4 acc1 = {0.f, 0.f, 0.f, 0.f};
#pragma unroll
    for (int ks = 0; ks < 4; ++ks) {
        acc0 = __builtin_amdgcn_mfma_f32_16x16x32_bf16(Af[ks], Bf[0][ks], acc0, 0, 0, 0);
        acc1 = __builtin_amdgcn_mfma_f32_16x16x32_bf16(Af[ks], Bf[1][ks], acc1, 0, 0, 0);
    }

    const int c0 = wv * 32 + r16;
    const float b0 = b[c0], b1 = b[c0 + 16];
#pragma unroll
    for (int r = 0; r < 4; ++r) {
        const size_t row = (size_t)(mb * 16 + quad * 4 + r) * 128;
        h8[row + c0]      = f32_to_fp8(acc0[r] + b0);
        h8[row + c0 + 16] = f32_to_fp8(acc1[r] + b1);
    }
}

// Block b: LDS histogram of its 12500-edge chunk (u16 counts packed 2/u32),
// LDS-atomic return = local rank. No global atomics (R3 lesson: 1.6M
// device-scope atomics = 103 MB EA round-trips).
__global__ __launch_bounds__(512) void hist_rank_kernel(const int* __restrict__ dst,
                                                        u32* __restrict__ hist,
                                                        u16* __restrict__ ranks) {
    __shared__ u32 hloc[NPAIR / 2];          // 12500 u32 = 50 KB
    const int b = blockIdx.x;
    const int base = b * CHUNK;
    u32* row = hist + (size_t)b * NPAIR;

#pragma unroll
    for (int half = 0; half < 2; ++half) {
        for (int j = threadIdx.x; j < NPAIR / 2; j += 512) hloc[j] = 0;
        __syncthreads();
        const int jlo = half * (NPAIR / 2);
        for (int i = threadIdx.x; i < CHUNK; i += 512) {
            const int d = dst[base + i];
            const int j = d >> 1;
            if ((j >= jlo) && (j < jlo + NPAIR / 2)) {
                const u32 inc = (d & 1) ? 0x10000u : 1u;
                const u32 old = atomicAdd(&hloc[j - jlo], inc);
                ranks[base + i] = (u16)((old >> ((d & 1) * 16)) & 0xFFFFu);
            }
        }
        __syncthreads();
        for (int j = threadIdx.x; j < NPAIR / 2; j += 512) row[jlo + j] = hloc[j];
        __syncthreads();
    }
}

// In-place exclusive scan over the NB block-rows for each node pair; emits deg.
__global__ void colscan_kernel(u32* __restrict__ hist, int* __restrict__ deg) {
    const int j = blockIdx.x * blockDim.x + threadIdx.x;
    if (j >= NPAIR) return;
    u32 lo = 0, hi = 0;
    u32* p = hist + j;
#pragma unroll 8
    for (int b = 0; b < NB; ++b) {
        const u32 v = p[(size_t)b * NPAIR];
        p[(size_t)b * NPAIR] = lo | (hi << 16);
        lo += v & 0xFFFFu;
        hi += v >> 16;
    }
    deg[2 * j]     = (int)lo;
    deg[2 * j + 1] = (int)hi;
}

// Single-block scan, fully unrolled + vectorized (R5 lesson: dynamic-trip
// scalar loops serialize ~100 round-trips). 13 int4/thread, all loads in
// flight before one waitcnt; deg tail pre-zeroed so row_start[50000]=E.
__global__ __launch_bounds__(1024) void scan_kernel(const int4* __restrict__ deg4,
                                                    int4* __restrict__ rs4) {
    __shared__ int part[1024];
    const int tid = threadIdx.x;
    int4 v[SCAN4];
#pragma unroll
    for (int j = 0; j < SCAN4; ++j) v[j] = deg4[tid * SCAN4 + j];
    int s = 0;
#pragma unroll
    for (int j = 0; j < SCAN4; ++j) s += v[j].x + v[j].y + v[j].z + v[j].w;
    part[tid] = s;
    __syncthreads();
    for (int d = 1; d < 1024; d <<= 1) {
        const int t = (tid >= d) ? part[tid - d] : 0;
        __syncthreads();
        part[tid] += t;
        __syncthreads();
    }
    int run = (tid == 0) ? 0 : part[tid - 1];
#pragma unroll
    for (int j = 0; j < SCAN4; ++j) {
        int4 o;
        o.x = run; run += v[j].x;
        o.y = run; run += v[j].y;
        o.z = run; run += v[j].z;
        o.w = run; run += v[j].w;
        rs4[tid * SCAN4 + j] = o;
    }
}

// pos = row_start[d] + colscan[b][d] + local_rank  -- atomic-free CSR fill.
__global__ __launch_bounds__(256) void fill_kernel(const int* __restrict__ src,
                                                   const int* __restrict__ dst,
                                                   const u16* __restrict__ ranks,
                                                   const int* __restrict__ row_start,
                                                   const u32* __restrict__ hist,
                                                   u16* __restrict__ csr) {
    const int b = blockIdx.x >> 2;
    const int q = blockIdx.x & 3;
    const u32* cs = hist + (size_t)b * NPAIR;
    const int base = b * CHUNK + q * (CHUNK / 4);
    for (int i = threadIdx.x; i < CHUNK / 4; i += 256) {
        const int d = dst[base + i];
        const int s = src[base + i];
        const int r = ranks[base + i];
        const int off = (int)((cs[d >> 1] >> ((d & 1) * 16)) & 0xFFFFu);
        csr[row_start[d] + off + r] = (u16)s;
    }
}

// One wave per dst node. fp8 rows (128B); half-wave k reads edge 2j+k, lane
// q=lane&31 holds 4 channels/dword. 8 edges per iteration = 4 independent
// load instructions in flight (R7 lesson: 1 load/iter was latency-bound at
// 88us; MLP is the fix, bandwidth floor is ~12us).
__global__ __launch_bounds__(256) void gather_kernel(const u32* __restrict__ h8d,
                                                     const int* __restrict__ row_start,
                                                     const u16* __restrict__ csr,
                                                     float* __restrict__ z_pad) {
    const int lane = threadIdx.x & 63;
    const int wv   = __builtin_amdgcn_readfirstlane((int)(threadIdx.x >> 6));
    const int q    = lane & 31;
    const bool h0  = lane < 32;
    const int o    = h0 ? 0 : 1;            // edge offset within pair
    const int gw   = blockIdx.x * 4 + wv;
    const int nw   = gridDim.x * 4;

    float z0 = 0.f, z1 = 0.f, z2 = 0.f, z3 = 0.f;
    for (int n = gw; n < N_NODES; n += nw) {
        const int rs  = row_start[n];
        const int cnt = row_start[n + 1] - rs;
        // self loop: count once (half 0 only)
        const u32 us = h8d[n * 32 + q];
        const f32x2 slo = __builtin_amdgcn_cvt_pk_f32_fp8(us, 0);
        const f32x2 shi = __builtin_amdgcn_cvt_pk_f32_fp8(us, 1);
        float a0 = h0 ? slo.x : 0.f;
        float a1 = h0 ? slo.y : 0.f;
        float a2 = h0 ? shi.x : 0.f;
        float a3 = h0 ? shi.y : 0.f;

        const u16* lst = csr + rs;
        int i = 0;
        for (; i + 8 <= cnt; i += 8) {       // 4 independent row-pair loads
            const int s0 = lst[i + 0 + o];
            const int s1 = lst[i + 2 + o];
            const int s2 = lst[i + 4 + o];
            const int s3 = lst[i + 6 + o];
            const u32 u0 = h8d[s0 * 32 + q];
            const u32 u1 = h8d[s1 * 32 + q];
            const u32 u2 = h8d[s2 * 32 + q];
            const u32 u3 = h8d[s3 * 32 + q];
            const f32x2 l0 = __builtin_amdgcn_cvt_pk_f32_fp8(u0, 0);
            const f32x2 g0 = __builtin_amdgcn_cvt_pk_f32_fp8(u0, 1);
            const f32x2 l1 = __builtin_amdgcn_cvt_pk_f32_fp8(u1, 0);
            const f32x2 g1 = __builtin_amdgcn_cvt_pk_f32_fp8(u1, 1);
            const f32x2 l2 = __builtin_amdgcn_cvt_pk_f32_fp8(u2, 0);
            const f32x2 g2 = __builtin_amdgcn_cvt_pk_f32_fp8(u2, 1);
            const f32x2 l3 = __builtin_amdgcn_cvt_pk_f32_fp8(u3, 0);
            const f32x2 g3 = __builtin_amdgcn_cvt_pk_f32_fp8(u3, 1);
            a0 += (l0.x + l1.x) + (l2.x + l3.x);
            a1 += (l0.y + l1.y) + (l2.y + l3.y);
            a2 += (g0.x + g1.x) + (g2.x + g3.x);
            a3 += (g0.y + g1.y) + (g2.y + g3.y);
        }
        for (; i + 2 <= cnt; i += 2) {
            const int s = lst[i + o];
            const u32 u = h8d[s * 32 + q];
            const f32x2 lo = __builtin_amdgcn_cvt_pk_f32_fp8(u, 0);
            const f32x2 hi = __builtin_amdgcn_cvt_pk_f32_fp8(u, 1);
            a0 += lo.x; a1 += lo.y; a2 += hi.x; a3 += hi.y;
        }
        if (i < cnt) {                        // odd tail: half 0 only
            const int s = lst[i];
            const u32 u = h8d[s * 32 + q];
            const f32x2 lo = __builtin_amdgcn_cvt_pk_f32_fp8(u, 0);
            const f32x2 hi = __builtin_amdgcn_cvt_pk_f32_fp8(u, 1);
            if (h0) { a0 += lo.x; a1 += lo.y; a2 += hi.x; a3 += hi.y; }
        }
        // combine halves (lane q <-> lane q+32)
        a0 += __shfl_xor(a0, 32);
        a1 += __shfl_xor(a1, 32);
        a2 += __shfl_xor(a2, 32);
        a3 += __shfl_xor(a3, 32);
        const float inv = 1.0f / (float)(cnt + 1);
        z0 += fmaxf(a0 * inv, 0.f);
        z1 += fmaxf(a1 * inv, 0.f);
        z2 += fmaxf(a2 * inv, 0.f);
        z3 += fmaxf(a3 * inv, 0.f);
    }

    // both halves hold identical z -> sum over all 64 lanes counts 2x; scale 0.5
    __shared__ float red[4][64][4];
    red[wv][lane][0] = z0;
    red[wv][lane][1] = z1;
    red[wv][lane][2] = z2;
    red[wv][lane][3] = z3;
    __syncthreads();
    if (threadIdx.x < 128) {
        const int c = threadIdx.x;          // channel
        const int g = c >> 2, m = c & 3;
        float s = 0.f;
#pragma unroll
        for (int w = 0; w < 4; ++w) s += red[w][g][m] + red[w][g + 32][m];
        atomicAdd(&z_pad[c * 32], 0.5f * s);   // 128 slots, 128B apart
    }
}

__global__ __launch_bounds__(512) void gru_kernel(const float* __restrict__ z_pad,
                                                  const float* __restrict__ W_ih,
                                                  const float* __restrict__ W_hh,
                                                  const float* __restrict__ b_ih,
                                                  const float* __restrict__ b_hh,
                                                  float* __restrict__ h_state,
                                                  const float* __restrict__ W_cls,
                                                  const float* __restrict__ b_cls,
                                                  float* __restrict__ out,
                                                  int do_cls) {
    __shared__ float zm[128], hs[128], gi[384], gh[384], hn[128];
    const int tid = threadIdx.x;
    if (tid < 128) {
        zm[tid] = z_pad[tid * 32] * (1.0f / (float)N_NODES);
        hs[tid] = h_state[tid];
    }
    __syncthreads();
    if (tid < 384) {
        float a = b_ih[tid], g = b_hh[tid];
        const float* wi = W_ih + tid * 128;
        const float* wh = W_hh + tid * 128;
#pragma unroll 8
        for (int k = 0; k < 128; ++k) {
            a = fmaf(zm[k], wi[k], a);
            g = fmaf(hs[k], wh[k], g);
        }
        gi[tid] = a;
        gh[tid] = g;
    }
    __syncthreads();
    if (tid < 128) {
        const float r  = 1.f / (1.f + expf(-(gi[tid] + gh[tid])));
        const float zg = 1.f / (1.f + expf(-(gi[128 + tid] + gh[128 + tid])));
        const float ng = tanhf(gi[256 + tid] + r * gh[256 + tid]);
        const float hv = (1.f - zg) * ng + zg * hs[tid];
        h_state[tid] = hv;
        hn[tid] = hv;
    }
    __syncthreads();
    if (do_cls && tid < OUT_CH) {
        float a = b_cls[tid];
        const float* wc = W_cls + tid * 128;
#pragma unroll 8
        for (int k = 0; k < 128; ++k) a = fmaf(hn[k], wc[k], a);
        out[tid] = a;
    }
}

extern "C" void kernel_launch(void* const* d_in, const int* in_sizes, int n_in,
                              void* d_out, int out_size, void* d_ws, size_t ws_size,
                              hipStream_t stream) {
    const float* xs    = (const float*)d_in[0];
    const int*   edges = (const int*)d_in[1];
    const float* W_gcn = (const float*)d_in[2];
    const float* b_gcn = (const float*)d_in[3];
    const float* W_ih  = (const float*)d_in[4];
    const float* W_hh  = (const float*)d_in[5];
    const float* b_ih  = (const float*)d_in[6];
    const float* b_hh  = (const float*)d_in[7];
    const float* W_cls = (const float*)d_in[8];
    const float* b_cls = (const float*)d_in[9];
    float* out = (float*)d_out;

    char* ws = (char*)d_ws;
    u8*    h8        = (u8*)(ws + OFF_H);
    int*   deg       = (int*)(ws + OFF_DEG);
    int*   row_start = (int*)(ws + OFF_RS);
    float* z_pad     = (float*)(ws + OFF_ZPAD);
    u16*   csr       = (u16*)(ws + OFF_CSR);
    float* h_state   = (float*)(ws + OFF_HST);
    __bf16* wb       = (__bf16*)(ws + OFF_WB);
    u16*   ranks     = (u16*)(ws + OFF_RANKS);
    u32*   hist      = (u32*)(ws + OFF_HIST);

    hipMemsetAsync(h_state, 0, 128 * sizeof(float), stream);
    // zero deg tail [50000, 13312*4): ws re-poisoned 0xAA before every launch
    hipMemsetAsync((char*)deg + 200000, 0, 13312 * 16 - 200000, stream);
    wbf_kernel<<<64, 256, 0, stream>>>(W_gcn, wb);

    for (int t = 0; t < T_STEPS; ++t) {
        const float* x_t  = xs + (size_t)t * N_NODES * 128;
        const int* src_t  = edges + (size_t)t * 2 * E_EDGES;
        const int* dst_t  = src_t + E_EDGES;

        hipMemsetAsync(z_pad, 0, 16384, stream);

        gemm_mfma_kernel<<<3125, 256, 0, stream>>>(x_t, wb, b_gcn, h8);
        hist_rank_kernel<<<NB, 512, 0, stream>>>(dst_t, hist, ranks);
        colscan_kernel<<<(NPAIR + 255) / 256, 256, 0, stream>>>(hist, deg);
        scan_kernel<<<1, 1024, 0, stream>>>((const int4*)deg, (int4*)row_start);
        fill_kernel<<<NB * 4, 256, 0, stream>>>(src_t, dst_t, ranks, row_start, hist, csr);
        gather_kernel<<<2048, 256, 0, stream>>>((const u32*)h8, row_start, csr, z_pad);
        gru_kernel<<<1, 512, 0, stream>>>(z_pad, W_ih, W_hh, b_ih, b_hh, h_state,
                                          W_cls, b_cls, out, (t == T_STEPS - 1) ? 1 : 0);
    }
}